// Round 1
// baseline (712.681 us; speedup 1.0000x reference)
//
#include <hip/hip_runtime.h>

typedef __attribute__((ext_vector_type(4))) float  f32x4;
typedef __attribute__((ext_vector_type(4))) int    i32x4;
typedef __attribute__((ext_vector_type(8))) __bf16 bf16x8;

constexpr int BM = 128, BN = 128, BK = 64;
constexpr int M_DIM = 8192, N_DIM = 4096, K_DIM = 4096;
constexpr int NT = K_DIM / BK;  // 64 K-steps

__global__ __launch_bounds__(256) void qlin_fused_gemm(
    const float* __restrict__ X, const int* __restrict__ P,
    const float* __restrict__ S, const float* __restrict__ Ofs,
    const float* __restrict__ Bias, float* __restrict__ Y)
{
  __shared__ __bf16 As[BM * BK];  // 16 KiB
  __shared__ __bf16 Bs[BN * BK];  // 16 KiB

  const int tid  = threadIdx.x;
  const int lane = tid & 63;
  const int wv   = tid >> 6;
  const int wr   = (wv >> 1) * 64;  // wave row origin in tile
  const int wc   = (wv & 1) * 64;   // wave col origin in tile

  const int bn0 = blockIdx.x * BN;
  const int bm0 = blockIdx.y * BM;

  // staging mapping: thread pair per row; each thread stages 32 k-elements
  const int srow  = tid >> 1;   // 0..127
  const int shalf = tid & 1;    // which 32-element half of the 64-wide k-tile

  const float* xrow = X + (size_t)(bm0 + srow) * K_DIM + shalf * 32;
  const int*   prow = P + (size_t)(bn0 + srow) * (K_DIM / 2) + shalf * 16;
  const int    gbase = (bn0 + srow) * (K_DIM / 128);  // group row base

  const int rowb = srow * (BK * 2);        // LDS row byte base
  const int sxor = (srow & 7) << 4;        // write-side swizzle
  const int cbb  = shalf * 64;             // byte col base of this thread's span

  f32x4 areg[8];
  i32x4 breg[4];
  float sc, of;

  f32x4 acc[4][4];
#pragma unroll
  for (int i = 0; i < 4; ++i)
#pragma unroll
    for (int j = 0; j < 4; ++j)
      acc[i][j] = (f32x4){0.f, 0.f, 0.f, 0.f};

  // prologue: load k-tile 0 into registers
#pragma unroll
  for (int i = 0; i < 8; ++i)
    areg[i] = *(const f32x4*)(xrow + 4 * i);
#pragma unroll
  for (int i = 0; i < 4; ++i)
    breg[i] = *(const i32x4*)(prow + 4 * i);
  sc = S[gbase];
  of = Ofs[gbase];

  for (int kt = 0; kt < NT; ++kt) {
    __syncthreads();  // previous compute done reading LDS (no-op on iter 0)

    // ---- stage A: fp32 -> bf16, swizzled ds_write_b128 ----
    {
      char* ab = (char*)As + rowb;
      char* bb = (char*)Bs + rowb;
#pragma unroll
      for (int i = 0; i < 4; ++i) {
        bf16x8 v;
        f32x4 u0 = areg[2 * i], u1 = areg[2 * i + 1];
        v[0] = (__bf16)u0[0]; v[1] = (__bf16)u0[1];
        v[2] = (__bf16)u0[2]; v[3] = (__bf16)u0[3];
        v[4] = (__bf16)u1[0]; v[5] = (__bf16)u1[1];
        v[6] = (__bf16)u1[2]; v[7] = (__bf16)u1[3];
        *(bf16x8*)(ab + ((cbb + 16 * i) ^ sxor)) = v;
      }
      // ---- stage B: int4 dequant -> bf16, swizzled ds_write_b128 ----
#pragma unroll
      for (int i = 0; i < 4; ++i) {
        bf16x8 v;
        i32x4 p = breg[i];
#pragma unroll
        for (int j = 0; j < 4; ++j) {
          int pv = p[j];
          float lo = (float)(pv & 15);         // even k: low nibble
          float hi = (float)((pv >> 4) & 15);  // odd k: high nibble
          v[2 * j]     = (__bf16)fmaf(lo, sc, of);
          v[2 * j + 1] = (__bf16)fmaf(hi, sc, of);
        }
        *(bf16x8*)(bb + ((cbb + 16 * i) ^ sxor)) = v;
      }
    }

    // prefetch next k-tile into registers (overlaps with compute below)
    if (kt + 1 < NT) {
      const float* xp = xrow + (kt + 1) * BK;
#pragma unroll
      for (int i = 0; i < 8; ++i)
        areg[i] = *(const f32x4*)(xp + 4 * i);
      const int* pp = prow + (kt + 1) * (BK / 2);
#pragma unroll
      for (int i = 0; i < 4; ++i)
        breg[i] = *(const i32x4*)(pp + 4 * i);
      int g = gbase + (kt + 1) / 2;  // group advances every 2 k-tiles
      sc = S[g];
      of = Ofs[g];
    }

    __syncthreads();  // LDS writes visible

    // ---- compute: 2 k-sub-steps x 16 MFMA ----
#pragma unroll
    for (int ks = 0; ks < 2; ++ks) {
      const int cb = ks * 64 + (lane >> 4) * 16;  // byte col of this lane's 8 bf16
      bf16x8 afr[4], bfr[4];
#pragma unroll
      for (int m = 0; m < 4; ++m) {
        int r = wr + m * 16 + (lane & 15);
        afr[m] = *(const bf16x8*)((const char*)As + r * (BK * 2) + (cb ^ ((r & 7) << 4)));
      }
#pragma unroll
      for (int n = 0; n < 4; ++n) {
        int r = wc + n * 16 + (lane & 15);
        bfr[n] = *(const bf16x8*)((const char*)Bs + r * (BK * 2) + (cb ^ ((r & 7) << 4)));
      }
#pragma unroll
      for (int m = 0; m < 4; ++m)
#pragma unroll
        for (int n = 0; n < 4; ++n)
          acc[m][n] = __builtin_amdgcn_mfma_f32_16x16x32_bf16(afr[m], bfr[n], acc[m][n], 0, 0, 0);
    }
  }

  // ---- epilogue: add bias, store fp32 ----
  // C/D layout: col = lane&15, row = (lane>>4)*4 + reg  [m89/m91 verified]
#pragma unroll
  for (int n = 0; n < 4; ++n) {
    const int col = bn0 + wc + n * 16 + (lane & 15);
    const float bias = Bias[col];
#pragma unroll
    for (int m = 0; m < 4; ++m) {
      const int row0 = bm0 + wr + m * 16 + (lane >> 4) * 4;
#pragma unroll
      for (int r = 0; r < 4; ++r) {
        Y[(size_t)(row0 + r) * N_DIM + col] = acc[m][n][r] + bias;
      }
    }
  }
}

extern "C" void kernel_launch(void* const* d_in, const int* in_sizes, int n_in,
                              void* d_out, int out_size, void* d_ws, size_t ws_size,
                              hipStream_t stream) {
  const float* X    = (const float*)d_in[0];
  const int*   P    = (const int*)d_in[1];
  const float* S    = (const float*)d_in[2];
  const float* Ofs  = (const float*)d_in[3];
  const float* Bias = (const float*)d_in[4];
  float* Y = (float*)d_out;

  dim3 grid(N_DIM / BN, M_DIM / BM);  // (32, 64)
  qlin_fused_gemm<<<grid, dim3(256), 0, stream>>>(X, P, S, Ofs, Bias, Y);
}

// Round 2
// 423.513 us; speedup vs baseline: 1.6828x; 1.6828x over previous
//
#include <hip/hip_runtime.h>
#include <stdint.h>

typedef __attribute__((ext_vector_type(4))) float  f32x4;
typedef __attribute__((ext_vector_type(4))) int    i32x4;
typedef __attribute__((ext_vector_type(8))) __bf16 bf16x8;

constexpr int M_DIM = 8192, N_DIM = 4096, K_DIM = 4096;
constexpr int BM = 128, BN = 128, BK = 64;
constexpr int NT = K_DIM / BK;  // 64 K-steps

// ---------------- pass 1a: X fp32 -> bf16 (memory-bound, vectorized) -------
__global__ __launch_bounds__(256) void cvt_x(const float* __restrict__ X,
                                             __bf16* __restrict__ Xb) {
  size_t i = ((size_t)blockIdx.x * 256 + threadIdx.x) * 8;
  const f32x4* src = (const f32x4*)(X + i);
  f32x4 a = src[0], b = src[1];
  bf16x8 v;
  v[0] = (__bf16)a[0]; v[1] = (__bf16)a[1]; v[2] = (__bf16)a[2]; v[3] = (__bf16)a[3];
  v[4] = (__bf16)b[0]; v[5] = (__bf16)b[1]; v[6] = (__bf16)b[2]; v[7] = (__bf16)b[3];
  *(bf16x8*)(Xb + i) = v;
}

// ------------- pass 1b: int4 group-dequant W -> bf16 [N][K] row-major ------
// packed: one int32 per BYTE value (2 nibbles -> 2 weights, [low, high])
__global__ __launch_bounds__(256) void deq_w(const int* __restrict__ P,
                                             const float* __restrict__ S,
                                             const float* __restrict__ O,
                                             __bf16* __restrict__ Wb) {
  size_t i = (size_t)blockIdx.x * 256 + threadIdx.x;  // handles 32 weights
  const i32x4* src = (const i32x4*)(P + i * 16);      // 16 ints = 32 weights
  int g = (int)(i >> 2);                              // 128 weights / group
  float s = S[g], o = O[g];
  __bf16* dst = Wb + i * 32;
#pragma unroll
  for (int j = 0; j < 4; ++j) {
    i32x4 p = src[j];
    bf16x8 v;
#pragma unroll
    for (int b = 0; b < 4; ++b) {
      int pv = p[b];
      v[2 * b]     = (__bf16)fmaf((float)(pv & 15), s, o);
      v[2 * b + 1] = (__bf16)fmaf((float)((pv >> 4) & 15), s, o);
    }
    *(bf16x8*)(dst + j * 8) = v;
  }
}

// ------------- pass 2: bf16 B^T GEMM, m97 structure (global_load_lds) ------
__global__ __launch_bounds__(256) void gemm_bt(const __bf16* __restrict__ A,
                                               const __bf16* __restrict__ B,
                                               const float* __restrict__ Bias,
                                               float* __restrict__ Y) {
  __shared__ __bf16 As[BM * BK];  // 16 KiB, linear [128][64]
  __shared__ __bf16 Bs[BN * BK];  // 16 KiB

  const int tid  = threadIdx.x;
  const int lane = tid & 63;
  const int w    = tid >> 6;
  const int wr   = (w >> 1) * 64;
  const int wc   = (w & 1) * 64;

  const int bn0 = blockIdx.x * BN;
  const int bm0 = blockIdx.y * BM;

  // staging geometry: segment s (1 KiB = 8 rows) per wave-call; lane covers 16 B
  const int sr = lane >> 3;         // row within segment
  const int cb = (lane & 7) * 16;   // byte col within row (64 bf16 = 128 B)

  f32x4 acc[4][4];
#pragma unroll
  for (int i = 0; i < 4; ++i)
#pragma unroll
    for (int j = 0; j < 4; ++j)
      acc[i][j] = (f32x4){0.f, 0.f, 0.f, 0.f};

  const size_t rowstride = (size_t)K_DIM * 2;  // bytes per operand row

  for (int kt = 0; kt < NT; ++kt) {
    __syncthreads();  // previous compute done reading LDS

    const char* abase = (const char*)A + (size_t)bm0 * rowstride + (size_t)kt * (BK * 2);
    const char* bbase = (const char*)B + (size_t)bn0 * rowstride + (size_t)kt * (BK * 2);
#pragma unroll
    for (int i = 0; i < 4; ++i) {
      const int s = w * 4 + i;          // wave-uniform segment id
      const int r = s * 8 + sr;         // per-lane global row
      __builtin_amdgcn_global_load_lds(
          (const __attribute__((address_space(1))) uint32_t*)(abase + (size_t)r * rowstride + cb),
          (__attribute__((address_space(3))) uint32_t*)((char*)As + s * 1024),
          16, 0, 0);
    }
#pragma unroll
    for (int i = 0; i < 4; ++i) {
      const int s = w * 4 + i;
      const int r = s * 8 + sr;
      __builtin_amdgcn_global_load_lds(
          (const __attribute__((address_space(1))) uint32_t*)(bbase + (size_t)r * rowstride + cb),
          (__attribute__((address_space(3))) uint32_t*)((char*)Bs + s * 1024),
          16, 0, 0);
    }

    __syncthreads();  // compiler drains vmcnt(0) before this barrier

#pragma unroll
    for (int ks = 0; ks < 2; ++ks) {
      const int col = ks * 64 + (lane >> 4) * 16;  // byte col of lane's 8 bf16
      bf16x8 afr[4], bfr[4];
#pragma unroll
      for (int m = 0; m < 4; ++m) {
        const int r = wr + m * 16 + (lane & 15);
        afr[m] = *(const bf16x8*)((const char*)As + r * (BK * 2) + col);
      }
#pragma unroll
      for (int n = 0; n < 4; ++n) {
        const int r = wc + n * 16 + (lane & 15);
        bfr[n] = *(const bf16x8*)((const char*)Bs + r * (BK * 2) + col);
      }
#pragma unroll
      for (int m = 0; m < 4; ++m)
#pragma unroll
        for (int n = 0; n < 4; ++n)
          acc[m][n] = __builtin_amdgcn_mfma_f32_16x16x32_bf16(afr[m], bfr[n], acc[m][n], 0, 0, 0);
    }
  }

  // epilogue: bias + fp32 store. C/D: col=lane&15, row=(lane>>4)*4+reg
#pragma unroll
  for (int n = 0; n < 4; ++n) {
    const int col = bn0 + wc + n * 16 + (lane & 15);
    const float bias = Bias[col];
#pragma unroll
    for (int m = 0; m < 4; ++m) {
      const int row0 = bm0 + wr + m * 16 + (lane >> 4) * 4;
#pragma unroll
      for (int r = 0; r < 4; ++r)
        Y[(size_t)(row0 + r) * N_DIM + col] = acc[m][n][r] + bias;
    }
  }
}

// ------------------- fallback: round-0 fused kernel ------------------------
__global__ __launch_bounds__(256) void qlin_fused_gemm(
    const float* __restrict__ X, const int* __restrict__ P,
    const float* __restrict__ S, const float* __restrict__ Ofs,
    const float* __restrict__ Bias, float* __restrict__ Y)
{
  __shared__ __bf16 As[BM * BK];
  __shared__ __bf16 Bs[BN * BK];

  const int tid  = threadIdx.x;
  const int lane = tid & 63;
  const int wv   = tid >> 6;
  const int wr   = (wv >> 1) * 64;
  const int wc   = (wv & 1) * 64;
  const int bn0 = blockIdx.x * BN;
  const int bm0 = blockIdx.y * BM;
  const int srow  = tid >> 1;
  const int shalf = tid & 1;

  const float* xrow = X + (size_t)(bm0 + srow) * K_DIM + shalf * 32;
  const int*   prow = P + (size_t)(bn0 + srow) * (K_DIM / 2) + shalf * 16;
  const int    gbase = (bn0 + srow) * (K_DIM / 128);

  const int rowb = srow * (BK * 2);
  const int sxor = (srow & 7) << 4;
  const int cbb  = shalf * 64;

  f32x4 areg[8];
  i32x4 breg[4];
  float sc, of;

  f32x4 acc[4][4];
#pragma unroll
  for (int i = 0; i < 4; ++i)
#pragma unroll
    for (int j = 0; j < 4; ++j)
      acc[i][j] = (f32x4){0.f, 0.f, 0.f, 0.f};

#pragma unroll
  for (int i = 0; i < 8; ++i) areg[i] = *(const f32x4*)(xrow + 4 * i);
#pragma unroll
  for (int i = 0; i < 4; ++i) breg[i] = *(const i32x4*)(prow + 4 * i);
  sc = S[gbase];
  of = Ofs[gbase];

  for (int kt = 0; kt < NT; ++kt) {
    __syncthreads();
    {
      char* ab = (char*)As + rowb;
      char* bb = (char*)Bs + rowb;
#pragma unroll
      for (int i = 0; i < 4; ++i) {
        bf16x8 v;
        f32x4 u0 = areg[2 * i], u1 = areg[2 * i + 1];
        v[0] = (__bf16)u0[0]; v[1] = (__bf16)u0[1];
        v[2] = (__bf16)u0[2]; v[3] = (__bf16)u0[3];
        v[4] = (__bf16)u1[0]; v[5] = (__bf16)u1[1];
        v[6] = (__bf16)u1[2]; v[7] = (__bf16)u1[3];
        *(bf16x8*)(ab + ((cbb + 16 * i) ^ sxor)) = v;
      }
#pragma unroll
      for (int i = 0; i < 4; ++i) {
        bf16x8 v;
        i32x4 p = breg[i];
#pragma unroll
        for (int j = 0; j < 4; ++j) {
          int pv = p[j];
          v[2 * j]     = (__bf16)fmaf((float)(pv & 15), sc, of);
          v[2 * j + 1] = (__bf16)fmaf((float)((pv >> 4) & 15), sc, of);
        }
        *(bf16x8*)(bb + ((cbb + 16 * i) ^ sxor)) = v;
      }
    }
    if (kt + 1 < NT) {
      const float* xp = xrow + (kt + 1) * BK;
#pragma unroll
      for (int i = 0; i < 8; ++i) areg[i] = *(const f32x4*)(xp + 4 * i);
      const int* pp = prow + (kt + 1) * (BK / 2);
#pragma unroll
      for (int i = 0; i < 4; ++i) breg[i] = *(const i32x4*)(pp + 4 * i);
      int g = gbase + (kt + 1) / 2;
      sc = S[g]; of = Ofs[g];
    }
    __syncthreads();
#pragma unroll
    for (int ks = 0; ks < 2; ++ks) {
      const int cb = ks * 64 + (lane >> 4) * 16;
      bf16x8 afr[4], bfr[4];
#pragma unroll
      for (int m = 0; m < 4; ++m) {
        int r = wr + m * 16 + (lane & 15);
        afr[m] = *(const bf16x8*)((const char*)As + r * (BK * 2) + (cb ^ ((r & 7) << 4)));
      }
#pragma unroll
      for (int n = 0; n < 4; ++n) {
        int r = wc + n * 16 + (lane & 15);
        bfr[n] = *(const bf16x8*)((const char*)Bs + r * (BK * 2) + (cb ^ ((r & 7) << 4)));
      }
#pragma unroll
      for (int m = 0; m < 4; ++m)
#pragma unroll
        for (int n = 0; n < 4; ++n)
          acc[m][n] = __builtin_amdgcn_mfma_f32_16x16x32_bf16(afr[m], bfr[n], acc[m][n], 0, 0, 0);
    }
  }
#pragma unroll
  for (int n = 0; n < 4; ++n) {
    const int col = bn0 + wc + n * 16 + (lane & 15);
    const float bias = Bias[col];
#pragma unroll
    for (int m = 0; m < 4; ++m) {
      const int row0 = bm0 + wr + m * 16 + (lane >> 4) * 4;
#pragma unroll
      for (int r = 0; r < 4; ++r)
        Y[(size_t)(row0 + r) * N_DIM + col] = acc[m][n][r] + bias;
    }
  }
}

extern "C" void kernel_launch(void* const* d_in, const int* in_sizes, int n_in,
                              void* d_out, int out_size, void* d_ws, size_t ws_size,
                              hipStream_t stream) {
  const float* X    = (const float*)d_in[0];
  const int*   P    = (const int*)d_in[1];
  const float* S    = (const float*)d_in[2];
  const float* Ofs  = (const float*)d_in[3];
  const float* Bias = (const float*)d_in[4];
  float* Y = (float*)d_out;

  const size_t xb_bytes = (size_t)M_DIM * K_DIM * 2;  // 67108864
  const size_t wb_bytes = (size_t)N_DIM * K_DIM * 2;  // 33554432

  if (ws_size >= xb_bytes + wb_bytes) {
    __bf16* Xb = (__bf16*)d_ws;
    __bf16* Wb = (__bf16*)((char*)d_ws + xb_bytes);

    cvt_x<<<dim3((M_DIM * K_DIM) / (256 * 8)), dim3(256), 0, stream>>>(X, Xb);
    deq_w<<<dim3((N_DIM * K_DIM) / (256 * 32)), dim3(256), 0, stream>>>(P, S, Ofs, Wb);

    dim3 grid(N_DIM / BN, M_DIM / BM);  // (32, 64)
    gemm_bt<<<grid, dim3(256), 0, stream>>>(Xb, Wb, Bias, Y);
  } else {
    dim3 grid(N_DIM / BN, M_DIM / BM);
    qlin_fused_gemm<<<grid, dim3(256), 0, stream>>>(X, P, S, Ofs, Bias, Y);
  }
}

// Round 3
// 307.571 us; speedup vs baseline: 2.3171x; 1.3770x over previous
//
#include <hip/hip_runtime.h>
#include <stdint.h>

typedef __attribute__((ext_vector_type(4))) float  f32x4;
typedef __attribute__((ext_vector_type(4))) int    i32x4;
typedef __attribute__((ext_vector_type(8))) __bf16 bf16x8;

constexpr int M_DIM = 8192, N_DIM = 4096, K_DIM = 4096;

#define VMCNT(n) asm volatile("s_waitcnt vmcnt(" #n ")" ::: "memory")
#define LGKMCNT0 asm volatile("s_waitcnt lgkmcnt(0)" ::: "memory")

// ---------------- pass 1a: X fp32 -> bf16 ----------------------------------
__global__ __launch_bounds__(256) void cvt_x(const float* __restrict__ X,
                                             __bf16* __restrict__ Xb) {
  size_t i = ((size_t)blockIdx.x * 256 + threadIdx.x) * 8;
  const f32x4* src = (const f32x4*)(X + i);
  f32x4 a = src[0], b = src[1];
  bf16x8 v;
  v[0] = (__bf16)a[0]; v[1] = (__bf16)a[1]; v[2] = (__bf16)a[2]; v[3] = (__bf16)a[3];
  v[4] = (__bf16)b[0]; v[5] = (__bf16)b[1]; v[6] = (__bf16)b[2]; v[7] = (__bf16)b[3];
  *(bf16x8*)(Xb + i) = v;
}

// ---------------- pass 1b: int4 group-dequant -> bf16 ----------------------
__global__ __launch_bounds__(256) void deq_w(const int* __restrict__ P,
                                             const float* __restrict__ S,
                                             const float* __restrict__ O,
                                             __bf16* __restrict__ Wb) {
  size_t i = (size_t)blockIdx.x * 256 + threadIdx.x;
  const i32x4* src = (const i32x4*)(P + i * 16);
  int g = (int)(i >> 2);
  float s = S[g], o = O[g];
  __bf16* dst = Wb + i * 32;
#pragma unroll
  for (int j = 0; j < 4; ++j) {
    i32x4 p = src[j];
    bf16x8 v;
#pragma unroll
    for (int b = 0; b < 4; ++b) {
      int pv = p[b];
      v[2 * b]     = (__bf16)fmaf((float)(pv & 15), s, o);
      v[2 * b + 1] = (__bf16)fmaf((float)((pv >> 4) & 15), s, o);
    }
    *(bf16x8*)(dst + j * 8) = v;
  }
}

// stage one 64-row x 64-col chunk (8 KiB) of a bf16 row-major operand.
// LDS dest is linear; global source col is pre-XOR-swizzled (rule #21).
__device__ __forceinline__ void stage64(const char* g, size_t rs, char* l, int tid) {
  const int r = tid >> 3;                              // 0..63 chunk-local row
  const int c = ((tid & 7) * 16) ^ ((r & 7) << 4);     // pre-swizzled source col
  __builtin_amdgcn_global_load_lds(
      (const __attribute__((address_space(1))) uint32_t*)(g + (size_t)r * rs + c),
      (__attribute__((address_space(3))) uint32_t*)(l + (tid >> 6) * 1024),
      16, 0, 0);
}

// ------------- pass 2: 256x256x64 8-phase bf16 GEMM (m201 structure) -------
__global__ __launch_bounds__(512, 2) void gemm8(const __bf16* __restrict__ A,
                                                const __bf16* __restrict__ B,
                                                const float* __restrict__ Bias,
                                                float* __restrict__ Y) {
  extern __shared__ char lds[];  // [A buf0|A buf1|B buf0|B buf1] = 4 x 32 KiB

  constexpr int NT = K_DIM / 64;
  const int tid  = threadIdx.x;
  const int lane = tid & 63;
  const int wid  = tid >> 6;
  const int wm   = wid >> 2;   // 0..1
  const int wn   = wid & 3;    // 0..3
  const int ln15 = lane & 15;
  const int lq   = lane >> 4;  // 0..3
  const int bn0  = blockIdx.x * 256;
  const int bm0  = blockIdx.y * 256;
  const size_t rs = (size_t)K_DIM * 2;

  const char* Ag = (const char*)A + (size_t)bm0 * rs;
  const char* Bg = (const char*)B + (size_t)bn0 * rs;

  f32x4 acc[8][4];
#pragma unroll
  for (int m = 0; m < 8; ++m)
#pragma unroll
    for (int n = 0; n < 4; ++n)
      acc[m][n] = (f32x4){0.f, 0.f, 0.f, 0.f};

  // ---- prologue: tile 0 -> buf0. Order: B x4, A-c0 x2, A-c1 x2 ----
  {
    char* Ab = lds;
    char* Bb = lds + 65536;
    stage64(Bg + (size_t)0 * rs,   rs, Bb + 0,     tid);
    stage64(Bg + (size_t)64 * rs,  rs, Bb + 8192,  tid);
    stage64(Bg + (size_t)128 * rs, rs, Bb + 16384, tid);
    stage64(Bg + (size_t)192 * rs, rs, Bb + 24576, tid);
    stage64(Ag + (size_t)0 * rs,   rs, Ab + 0,     tid);
    stage64(Ag + (size_t)128 * rs, rs, Ab + 16384, tid);
    stage64(Ag + (size_t)64 * rs,  rs, Ab + 8192,  tid);
    stage64(Ag + (size_t)192 * rs, rs, Ab + 24576, tid);
  }
  VMCNT(2);                      // B + A-c0 of tile 0 landed; A-c1 may fly
  __builtin_amdgcn_s_barrier();

  for (int t = 0; t < NT; ++t) {
    const char* Ab = lds + (t & 1) * 32768;
    const char* Bb = lds + 65536 + (t & 1) * 32768;
    char* An = lds + ((t + 1) & 1) * 32768;
    char* Bn = lds + 65536 + ((t + 1) & 1) * 32768;
    const bool st = (t + 1 < NT);
    const char* ga = Ag + (size_t)(t + 1) * 128;  // next tile k-slice (bytes)
    const char* gb = Bg + (size_t)(t + 1) * 128;

#pragma unroll
    for (int q = 0; q < 4; ++q) {            // 4 phases per K-tile
      const int mh = q >> 1, nh = q & 1;     // C-quadrant
      __builtin_amdgcn_sched_barrier(0);     // pin phase loads below prev barrier

      // ---- ds_read register subtile (8 A-frags + 4 B-frags) ----
      bf16x8 af[4][2], bfr[2][2];
#pragma unroll
      for (int m4 = 0; m4 < 4; ++m4) {
        const int r  = wm * 128 + (mh * 4 + m4) * 16 + ln15;
        const int sw = (r & 7) << 4;
#pragma unroll
        for (int ks = 0; ks < 2; ++ks)
          af[m4][ks] = *(const bf16x8*)(Ab + r * 128 + ((ks * 64 + lq * 16) ^ sw));
      }
#pragma unroll
      for (int n2 = 0; n2 < 2; ++n2) {
        const int r  = wn * 64 + (nh * 2 + n2) * 16 + ln15;
        const int sw = (r & 7) << 4;
#pragma unroll
        for (int ks = 0; ks < 2; ++ks)
          bfr[n2][ks] = *(const bf16x8*)(Bb + r * 128 + ((ks * 64 + lq * 16) ^ sw));
      }

      // ---- stage 2 chunks of tile t+1 (B first, then A-c0, A-c1) ----
      if (st) {
        if (q == 0) { stage64(gb, rs, Bn, tid);
                      stage64(gb + (size_t)64 * rs, rs, Bn + 8192, tid); }
        if (q == 1) { stage64(gb + (size_t)128 * rs, rs, Bn + 16384, tid);
                      stage64(gb + (size_t)192 * rs, rs, Bn + 24576, tid); }
        if (q == 2) { stage64(ga, rs, An, tid);
                      stage64(ga + (size_t)128 * rs, rs, An + 16384, tid); }
        if (q == 3) { stage64(ga + (size_t)64 * rs, rs, An + 8192, tid);
                      stage64(ga + (size_t)192 * rs, rs, An + 24576, tid); }
      }

      __builtin_amdgcn_s_barrier();
      LGKMCNT0;
      __builtin_amdgcn_sched_barrier(0);     // rule #18: don't hoist MFMA above wait

      __builtin_amdgcn_s_setprio(1);
#pragma unroll
      for (int ks = 0; ks < 2; ++ks)
#pragma unroll
        for (int m4 = 0; m4 < 4; ++m4)
#pragma unroll
          for (int n2 = 0; n2 < 2; ++n2)
            acc[mh * 4 + m4][nh * 2 + n2] = __builtin_amdgcn_mfma_f32_16x16x32_bf16(
                af[m4][ks], bfr[n2][ks], acc[mh * 4 + m4][nh * 2 + n2], 0, 0, 0);
      __builtin_amdgcn_s_setprio(0);
      __builtin_amdgcn_sched_barrier(0);

      // counted waits, never 0 in steady state (T4):
      if (q == 1) {                 // before q2/q3 read A-c1 of tile t
        if (t == NT - 1) { VMCNT(0); } else { VMCNT(4); }
      }
      if (q == 3) { VMCNT(2); }     // before next tile's q0 reads B + A-c0
      __builtin_amdgcn_s_barrier();
    }
  }

  // ---- epilogue: bias + fp32 store. C/D: col=lane&15, row=(lane>>4)*4+reg ----
#pragma unroll
  for (int n = 0; n < 4; ++n) {
    const int col = bn0 + wn * 64 + n * 16 + ln15;
    const float bias = Bias[col];
#pragma unroll
    for (int m = 0; m < 8; ++m) {
      const int row0 = bm0 + wm * 128 + m * 16 + lq * 4;
#pragma unroll
      for (int r = 0; r < 4; ++r)
        Y[(size_t)(row0 + r) * N_DIM + col] = acc[m][n][r] + bias;
    }
  }
}

// ------------------- fallback: round-0 fused kernel ------------------------
__global__ __launch_bounds__(256) void qlin_fused_gemm(
    const float* __restrict__ X, const int* __restrict__ P,
    const float* __restrict__ S, const float* __restrict__ Ofs,
    const float* __restrict__ Bias, float* __restrict__ Y)
{
  constexpr int BM = 128, BN = 128, BK = 64;
  constexpr int NT = K_DIM / BK;
  __shared__ __bf16 As[BM * BK];
  __shared__ __bf16 Bs[BN * BK];

  const int tid  = threadIdx.x;
  const int lane = tid & 63;
  const int wv   = tid >> 6;
  const int wr   = (wv >> 1) * 64;
  const int wc   = (wv & 1) * 64;
  const int bn0 = blockIdx.x * BN;
  const int bm0 = blockIdx.y * BM;
  const int srow  = tid >> 1;
  const int shalf = tid & 1;

  const float* xrow = X + (size_t)(bm0 + srow) * K_DIM + shalf * 32;
  const int*   prow = P + (size_t)(bn0 + srow) * (K_DIM / 2) + shalf * 16;
  const int    gbase = (bn0 + srow) * (K_DIM / 128);

  const int rowb = srow * (BK * 2);
  const int sxor = (srow & 7) << 4;
  const int cbb  = shalf * 64;

  f32x4 areg[8];
  i32x4 breg[4];
  float sc, of;

  f32x4 acc[4][4];
#pragma unroll
  for (int i = 0; i < 4; ++i)
#pragma unroll
    for (int j = 0; j < 4; ++j)
      acc[i][j] = (f32x4){0.f, 0.f, 0.f, 0.f};

#pragma unroll
  for (int i = 0; i < 8; ++i) areg[i] = *(const f32x4*)(xrow + 4 * i);
#pragma unroll
  for (int i = 0; i < 4; ++i) breg[i] = *(const i32x4*)(prow + 4 * i);
  sc = S[gbase];
  of = Ofs[gbase];

  for (int kt = 0; kt < NT; ++kt) {
    __syncthreads();
    {
      char* ab = (char*)As + rowb;
      char* bb = (char*)Bs + rowb;
#pragma unroll
      for (int i = 0; i < 4; ++i) {
        bf16x8 v;
        f32x4 u0 = areg[2 * i], u1 = areg[2 * i + 1];
        v[0] = (__bf16)u0[0]; v[1] = (__bf16)u0[1];
        v[2] = (__bf16)u0[2]; v[3] = (__bf16)u0[3];
        v[4] = (__bf16)u1[0]; v[5] = (__bf16)u1[1];
        v[6] = (__bf16)u1[2]; v[7] = (__bf16)u1[3];
        *(bf16x8*)(ab + ((cbb + 16 * i) ^ sxor)) = v;
      }
#pragma unroll
      for (int i = 0; i < 4; ++i) {
        bf16x8 v;
        i32x4 p = breg[i];
#pragma unroll
        for (int j = 0; j < 4; ++j) {
          int pv = p[j];
          v[2 * j]     = (__bf16)fmaf((float)(pv & 15), sc, of);
          v[2 * j + 1] = (__bf16)fmaf((float)((pv >> 4) & 15), sc, of);
        }
        *(bf16x8*)(bb + ((cbb + 16 * i) ^ sxor)) = v;
      }
    }
    if (kt + 1 < NT) {
      const float* xp = xrow + (kt + 1) * BK;
#pragma unroll
      for (int i = 0; i < 8; ++i) areg[i] = *(const f32x4*)(xp + 4 * i);
      const int* pp = prow + (kt + 1) * (BK / 2);
#pragma unroll
      for (int i = 0; i < 4; ++i) breg[i] = *(const i32x4*)(pp + 4 * i);
      int g = gbase + (kt + 1) / 2;
      sc = S[g]; of = Ofs[g];
    }
    __syncthreads();
#pragma unroll
    for (int ks = 0; ks < 2; ++ks) {
      const int cb = ks * 64 + (lane >> 4) * 16;
      bf16x8 afr[4], bfr[4];
#pragma unroll
      for (int m = 0; m < 4; ++m) {
        int r = wr + m * 16 + (lane & 15);
        afr[m] = *(const bf16x8*)((const char*)As + r * (BK * 2) + (cb ^ ((r & 7) << 4)));
      }
#pragma unroll
      for (int n = 0; n < 4; ++n) {
        int r = wc + n * 16 + (lane & 15);
        bfr[n] = *(const bf16x8*)((const char*)Bs + r * (BK * 2) + (cb ^ ((r & 7) << 4)));
      }
#pragma unroll
      for (int m = 0; m < 4; ++m)
#pragma unroll
        for (int n = 0; n < 4; ++n)
          acc[m][n] = __builtin_amdgcn_mfma_f32_16x16x32_bf16(afr[m], bfr[n], acc[m][n], 0, 0, 0);
    }
  }
#pragma unroll
  for (int n = 0; n < 4; ++n) {
    const int col = bn0 + wc + n * 16 + (lane & 15);
    const float bias = Bias[col];
#pragma unroll
    for (int m = 0; m < 4; ++m) {
      const int row0 = bm0 + wr + m * 16 + (lane >> 4) * 4;
#pragma unroll
      for (int r = 0; r < 4; ++r)
        Y[(size_t)(row0 + r) * N_DIM + col] = acc[m][n][r] + bias;
    }
  }
}

extern "C" void kernel_launch(void* const* d_in, const int* in_sizes, int n_in,
                              void* d_out, int out_size, void* d_ws, size_t ws_size,
                              hipStream_t stream) {
  const float* X    = (const float*)d_in[0];
  const int*   P    = (const int*)d_in[1];
  const float* S    = (const float*)d_in[2];
  const float* Ofs  = (const float*)d_in[3];
  const float* Bias = (const float*)d_in[4];
  float* Y = (float*)d_out;

  const size_t xb_bytes = (size_t)M_DIM * K_DIM * 2;
  const size_t wb_bytes = (size_t)N_DIM * K_DIM * 2;

  if (ws_size >= xb_bytes + wb_bytes) {
    __bf16* Xb = (__bf16*)d_ws;
    __bf16* Wb = (__bf16*)((char*)d_ws + xb_bytes);

    cvt_x<<<dim3((M_DIM * K_DIM) / (256 * 8)), dim3(256), 0, stream>>>(X, Xb);
    deq_w<<<dim3((N_DIM * K_DIM) / (256 * 32)), dim3(256), 0, stream>>>(P, S, Ofs, Wb);

    hipFuncSetAttribute((const void*)gemm8,
                        hipFuncAttributeMaxDynamicSharedMemorySize, 131072);
    dim3 grid(N_DIM / 256, M_DIM / 256);  // (16, 32)
    gemm8<<<grid, dim3(512), 131072, stream>>>(Xb, Wb, Bias, Y);
  } else {
    dim3 grid(N_DIM / 128, M_DIM / 128);
    qlin_fused_gemm<<<grid, dim3(256), 0, stream>>>(X, P, S, Ofs, Bias, Y);
  }
}

// Round 4
// 275.365 us; speedup vs baseline: 2.5881x; 1.1170x over previous
//
#include <hip/hip_runtime.h>
#include <stdint.h>

typedef __attribute__((ext_vector_type(4))) float  f32x4;
typedef __attribute__((ext_vector_type(4))) int    i32x4;
typedef __attribute__((ext_vector_type(8))) __bf16 bf16x8;

constexpr int M_DIM = 8192, N_DIM = 4096, K_DIM = 4096;

#define VMCNT(n) asm volatile("s_waitcnt vmcnt(" #n ")" ::: "memory")
#define LGKMCNT0 asm volatile("s_waitcnt lgkmcnt(0)" ::: "memory")

// ---------------- pass 1a: X fp32 -> bf16 ----------------------------------
__global__ __launch_bounds__(256) void cvt_x(const float* __restrict__ X,
                                             __bf16* __restrict__ Xb) {
  size_t i = ((size_t)blockIdx.x * 256 + threadIdx.x) * 8;
  const f32x4* src = (const f32x4*)(X + i);
  f32x4 a = src[0], b = src[1];
  bf16x8 v;
  v[0] = (__bf16)a[0]; v[1] = (__bf16)a[1]; v[2] = (__bf16)a[2]; v[3] = (__bf16)a[3];
  v[4] = (__bf16)b[0]; v[5] = (__bf16)b[1]; v[6] = (__bf16)b[2]; v[7] = (__bf16)b[3];
  *(bf16x8*)(Xb + i) = v;
}

// ---------------- pass 1b: int4 group-dequant -> bf16 ----------------------
__global__ __launch_bounds__(256) void deq_w(const int* __restrict__ P,
                                             const float* __restrict__ S,
                                             const float* __restrict__ O,
                                             __bf16* __restrict__ Wb) {
  size_t i = (size_t)blockIdx.x * 256 + threadIdx.x;
  const i32x4* src = (const i32x4*)(P + i * 16);
  int g = (int)(i >> 2);
  float s = S[g], o = O[g];
  __bf16* dst = Wb + i * 32;
#pragma unroll
  for (int j = 0; j < 4; ++j) {
    i32x4 p = src[j];
    bf16x8 v;
#pragma unroll
    for (int b = 0; b < 4; ++b) {
      int pv = p[b];
      v[2 * b]     = (__bf16)fmaf((float)(pv & 15), s, o);
      v[2 * b + 1] = (__bf16)fmaf((float)((pv >> 4) & 15), s, o);
    }
    *(bf16x8*)(dst + j * 8) = v;
  }
}

// stage one 64-row x 64-col chunk (8 KiB) of a bf16 row-major operand.
// LDS dest is linear; global source col is pre-XOR-swizzled (rule #21).
__device__ __forceinline__ void stage64(const char* g, size_t rs, char* l, int tid) {
  const int r = tid >> 3;                              // 0..63 chunk-local row
  const int c = ((tid & 7) * 16) ^ ((r & 7) << 4);     // pre-swizzled source col
  __builtin_amdgcn_global_load_lds(
      (const __attribute__((address_space(1))) uint32_t*)(g + (size_t)r * rs + c),
      (__attribute__((address_space(3))) uint32_t*)(l + (tid >> 6) * 1024),
      16, 0, 0);
}

// ------- pass 2: 256x256x64 8-phase bf16 GEMM, minimal ds_read variant -----
__global__ __launch_bounds__(512, 2) void gemm8(const __bf16* __restrict__ A,
                                                const __bf16* __restrict__ B,
                                                const float* __restrict__ Bias,
                                                float* __restrict__ Y) {
  extern __shared__ char lds[];  // [A buf0|A buf1|B buf0|B buf1] = 4 x 32 KiB

  constexpr int NT = K_DIM / 64;
  const int tid  = threadIdx.x;
  const int lane = tid & 63;
  const int wid  = tid >> 6;
  const int wm   = wid >> 2;   // 0..1
  const int wn   = wid & 3;    // 0..3
  const int ln15 = lane & 15;
  const int lq   = lane >> 4;  // 0..3

  // T1: bijective XCD swizzle (nwg = 512, 512 % 8 == 0)
  const int id  = blockIdx.y * gridDim.x + blockIdx.x;
  const int swz = (id & 7) * 64 + (id >> 3);
  const int bn0 = (swz & 15) * 256;   // gridDim.x = 16
  const int bm0 = (swz >> 4) * 256;

  const size_t rs = (size_t)K_DIM * 2;
  const char* Ag = (const char*)A + (size_t)bm0 * rs;
  const char* Bg = (const char*)B + (size_t)bn0 * rs;

  f32x4 acc[8][4];
#pragma unroll
  for (int m = 0; m < 8; ++m)
#pragma unroll
    for (int n = 0; n < 4; ++n)
      acc[m][n] = (f32x4){0.f, 0.f, 0.f, 0.f};

  // ---- prologue: tile 0 -> buf0. Issue order: B x4, A0, A2, A1, A3 ----
  {
    char* Ab = lds;
    char* Bb = lds + 65536;
    stage64(Bg + (size_t)0 * rs,   rs, Bb + 0,     tid);
    stage64(Bg + (size_t)64 * rs,  rs, Bb + 8192,  tid);
    stage64(Bg + (size_t)128 * rs, rs, Bb + 16384, tid);
    stage64(Bg + (size_t)192 * rs, rs, Bb + 24576, tid);
    stage64(Ag + (size_t)0 * rs,   rs, Ab + 0,     tid);
    stage64(Ag + (size_t)128 * rs, rs, Ab + 16384, tid);
    stage64(Ag + (size_t)64 * rs,  rs, Ab + 8192,  tid);
    stage64(Ag + (size_t)192 * rs, rs, Ab + 24576, tid);
  }
  VMCNT(2);                      // B(all) + A0 + A2 landed; A1,A3 may fly
  __builtin_amdgcn_s_barrier();

  for (int t = 0; t < NT; ++t) {
    const char* Ab = lds + (t & 1) * 32768;
    const char* Bb = lds + 65536 + (t & 1) * 32768;
    char* An = lds + ((t + 1) & 1) * 32768;
    char* Bn = lds + 65536 + ((t + 1) & 1) * 32768;
    const bool st = (t + 1 < NT);
    const char* ga = Ag + (size_t)(t + 1) * 128;  // next tile k-slice (bytes)
    const char* gb = Bg + (size_t)(t + 1) * 128;

    bf16x8 bfr[4];  // wave's B-band frags for current ks-half, reused 2 phases

    // phases q = (ks<<1) | mh :  q0:(ks0,mh0) q1:(ks0,mh1) q2:(ks1,mh0) q3:(ks1,mh1)
#pragma unroll
    for (int q = 0; q < 4; ++q) {
      const int mh = q & 1, ks = q >> 1;
      __builtin_amdgcn_sched_barrier(0);

      // ---- ds_read: B frags once per ks (4), A frags every phase (4) ----
      if (mh == 0) {
#pragma unroll
        for (int n = 0; n < 4; ++n) {
          const int r  = wn * 64 + n * 16 + ln15;
          const int sw = (r & 7) << 4;
          bfr[n] = *(const bf16x8*)(Bb + r * 128 + ((ks * 64 + lq * 16) ^ sw));
        }
      }
      bf16x8 af[4];
#pragma unroll
      for (int m4 = 0; m4 < 4; ++m4) {
        const int r  = wm * 128 + (mh * 4 + m4) * 16 + ln15;
        const int sw = (r & 7) << 4;
        af[m4] = *(const bf16x8*)(Ab + r * 128 + ((ks * 64 + lq * 16) ^ sw));
      }

      // ---- stage 2 chunks of tile t+1 ----
      if (st) {
        if (q == 0) { stage64(gb, rs, Bn, tid);
                      stage64(gb + (size_t)64 * rs, rs, Bn + 8192, tid); }
        if (q == 1) { stage64(gb + (size_t)128 * rs, rs, Bn + 16384, tid);
                      stage64(gb + (size_t)192 * rs, rs, Bn + 24576, tid); }
        if (q == 2) { stage64(ga, rs, An, tid);
                      stage64(ga + (size_t)128 * rs, rs, An + 16384, tid); }
        if (q == 3) { stage64(ga + (size_t)64 * rs, rs, An + 8192, tid);
                      stage64(ga + (size_t)192 * rs, rs, An + 24576, tid); }
      }

      __builtin_amdgcn_s_barrier();
      LGKMCNT0;
      __builtin_amdgcn_sched_barrier(0);     // rule #18

      __builtin_amdgcn_s_setprio(1);
#pragma unroll
      for (int m4 = 0; m4 < 4; ++m4)
#pragma unroll
        for (int n = 0; n < 4; ++n)
          acc[mh * 4 + m4][n] = __builtin_amdgcn_mfma_f32_16x16x32_bf16(
              af[m4], bfr[n], acc[mh * 4 + m4][n], 0, 0, 0);
      __builtin_amdgcn_s_setprio(0);
      __builtin_amdgcn_sched_barrier(0);

      // counted waits (T4), never 0 in steady state:
      if (q == 0) {                 // q1 reads A1,A3 of tile t
        if (t == NT - 1) { VMCNT(0); } else { VMCNT(2); }
      }
      if (q == 3 && st) { VMCNT(2); }  // next q0 reads B(all)+A0+A2 of t+1
      __builtin_amdgcn_s_barrier();
    }
  }

  // ---- epilogue: bias + fp32 store. C/D: col=lane&15, row=(lane>>4)*4+reg ----
#pragma unroll
  for (int n = 0; n < 4; ++n) {
    const int col = bn0 + wn * 64 + n * 16 + ln15;
    const float bias = Bias[col];
#pragma unroll
    for (int m = 0; m < 8; ++m) {
      const int row0 = bm0 + wm * 128 + m * 16 + lq * 4;
#pragma unroll
      for (int r = 0; r < 4; ++r)
        Y[(size_t)(row0 + r) * N_DIM + col] = acc[m][n][r] + bias;
    }
  }
}

// ------------------- fallback: round-0 fused kernel ------------------------
__global__ __launch_bounds__(256) void qlin_fused_gemm(
    const float* __restrict__ X, const int* __restrict__ P,
    const float* __restrict__ S, const float* __restrict__ Ofs,
    const float* __restrict__ Bias, float* __restrict__ Y)
{
  constexpr int BM = 128, BN = 128, BK = 64;
  constexpr int NT = K_DIM / BK;
  __shared__ __bf16 As[BM * BK];
  __shared__ __bf16 Bs[BN * BK];

  const int tid  = threadIdx.x;
  const int lane = tid & 63;
  const int wv   = tid >> 6;
  const int wr   = (wv >> 1) * 64;
  const int wc   = (wv & 1) * 64;
  const int bn0 = blockIdx.x * BN;
  const int bm0 = blockIdx.y * BM;
  const int srow  = tid >> 1;
  const int shalf = tid & 1;

  const float* xrow = X + (size_t)(bm0 + srow) * K_DIM + shalf * 32;
  const int*   prow = P + (size_t)(bn0 + srow) * (K_DIM / 2) + shalf * 16;
  const int    gbase = (bn0 + srow) * (K_DIM / 128);

  const int rowb = srow * (BK * 2);
  const int sxor = (srow & 7) << 4;
  const int cbb  = shalf * 64;

  f32x4 areg[8];
  i32x4 breg[4];
  float sc, of;

  f32x4 acc[4][4];
#pragma unroll
  for (int i = 0; i < 4; ++i)
#pragma unroll
    for (int j = 0; j < 4; ++j)
      acc[i][j] = (f32x4){0.f, 0.f, 0.f, 0.f};

#pragma unroll
  for (int i = 0; i < 8; ++i) areg[i] = *(const f32x4*)(xrow + 4 * i);
#pragma unroll
  for (int i = 0; i < 4; ++i) breg[i] = *(const i32x4*)(prow + 4 * i);
  sc = S[gbase];
  of = Ofs[gbase];

  for (int kt = 0; kt < NT; ++kt) {
    __syncthreads();
    {
      char* ab = (char*)As + rowb;
      char* bb = (char*)Bs + rowb;
#pragma unroll
      for (int i = 0; i < 4; ++i) {
        bf16x8 v;
        f32x4 u0 = areg[2 * i], u1 = areg[2 * i + 1];
        v[0] = (__bf16)u0[0]; v[1] = (__bf16)u0[1];
        v[2] = (__bf16)u0[2]; v[3] = (__bf16)u0[3];
        v[4] = (__bf16)u1[0]; v[5] = (__bf16)u1[1];
        v[6] = (__bf16)u1[2]; v[7] = (__bf16)u1[3];
        *(bf16x8*)(ab + ((cbb + 16 * i) ^ sxor)) = v;
      }
#pragma unroll
      for (int i = 0; i < 4; ++i) {
        bf16x8 v;
        i32x4 p = breg[i];
#pragma unroll
        for (int j = 0; j < 4; ++j) {
          int pv = p[j];
          v[2 * j]     = (__bf16)fmaf((float)(pv & 15), sc, of);
          v[2 * j + 1] = (__bf16)fmaf((float)((pv >> 4) & 15), sc, of);
        }
        *(bf16x8*)(bb + ((cbb + 16 * i) ^ sxor)) = v;
      }
    }
    if (kt + 1 < NT) {
      const float* xp = xrow + (kt + 1) * BK;
#pragma unroll
      for (int i = 0; i < 8; ++i) areg[i] = *(const f32x4*)(xp + 4 * i);
      const int* pp = prow + (kt + 1) * (BK / 2);
#pragma unroll
      for (int i = 0; i < 4; ++i) breg[i] = *(const i32x4*)(pp + 4 * i);
      int g = gbase + (kt + 1) / 2;
      sc = S[g]; of = Ofs[g];
    }
    __syncthreads();
#pragma unroll
    for (int ks = 0; ks < 2; ++ks) {
      const int cb = ks * 64 + (lane >> 4) * 16;
      bf16x8 afr[4], bfr[4];
#pragma unroll
      for (int m = 0; m < 4; ++m) {
        int r = wr + m * 16 + (lane & 15);
        afr[m] = *(const bf16x8*)((const char*)As + r * (BK * 2) + (cb ^ ((r & 7) << 4)));
      }
#pragma unroll
      for (int n = 0; n < 4; ++n) {
        int r = wc + n * 16 + (lane & 15);
        bfr[n] = *(const bf16x8*)((const char*)Bs + r * (BK * 2) + (cb ^ ((r & 7) << 4)));
      }
#pragma unroll
      for (int m = 0; m < 4; ++m)
#pragma unroll
        for (int n = 0; n < 4; ++n)
          acc[m][n] = __builtin_amdgcn_mfma_f32_16x16x32_bf16(afr[m], bfr[n], acc[m][n], 0, 0, 0);
    }
  }
#pragma unroll
  for (int n = 0; n < 4; ++n) {
    const int col = bn0 + wc + n * 16 + (lane & 15);
    const float bias = Bias[col];
#pragma unroll
    for (int m = 0; m < 4; ++m) {
      const int row0 = bm0 + wr + m * 16 + (lane >> 4) * 4;
#pragma unroll
      for (int r = 0; r < 4; ++r)
        Y[(size_t)(row0 + r) * N_DIM + col] = acc[m][n][r] + bias;
    }
  }
}

extern "C" void kernel_launch(void* const* d_in, const int* in_sizes, int n_in,
                              void* d_out, int out_size, void* d_ws, size_t ws_size,
                              hipStream_t stream) {
  const float* X    = (const float*)d_in[0];
  const int*   P    = (const int*)d_in[1];
  const float* S    = (const float*)d_in[2];
  const float* Ofs  = (const float*)d_in[3];
  const float* Bias = (const float*)d_in[4];
  float* Y = (float*)d_out;

  const size_t xb_bytes = (size_t)M_DIM * K_DIM * 2;
  const size_t wb_bytes = (size_t)N_DIM * K_DIM * 2;

  if (ws_size >= xb_bytes + wb_bytes) {
    __bf16* Xb = (__bf16*)d_ws;
    __bf16* Wb = (__bf16*)((char*)d_ws + xb_bytes);

    cvt_x<<<dim3((M_DIM * K_DIM) / (256 * 8)), dim3(256), 0, stream>>>(X, Xb);
    deq_w<<<dim3((N_DIM * K_DIM) / (256 * 32)), dim3(256), 0, stream>>>(P, S, Ofs, Wb);

    hipFuncSetAttribute((const void*)gemm8,
                        hipFuncAttributeMaxDynamicSharedMemorySize, 131072);
    dim3 grid(N_DIM / 256, M_DIM / 256);  // (16, 32)
    gemm8<<<grid, dim3(512), 131072, stream>>>(Xb, Wb, Bias, Y);
  } else {
    dim3 grid(N_DIM / 128, M_DIM / 128);
    qlin_fused_gemm<<<grid, dim3(256), 0, stream>>>(X, P, S, Ofs, Bias, Y);
  }
}

// Round 5
// 268.374 us; speedup vs baseline: 2.6556x; 1.0260x over previous
//
#include <hip/hip_runtime.h>
#include <stdint.h>

typedef __attribute__((ext_vector_type(4))) float  f32x4;
typedef __attribute__((ext_vector_type(4))) int    i32x4;
typedef __attribute__((ext_vector_type(8))) __bf16 bf16x8;

constexpr int M_DIM = 8192, N_DIM = 4096, K_DIM = 4096;

#define VMCNT(n) asm volatile("s_waitcnt vmcnt(" #n ")" ::: "memory")
#define LGKMCNT0 asm volatile("s_waitcnt lgkmcnt(0)" ::: "memory")
#define SB __builtin_amdgcn_sched_barrier(0)

// ---------------- pass 1a: X fp32 -> bf16 ----------------------------------
__global__ __launch_bounds__(256) void cvt_x(const float* __restrict__ X,
                                             __bf16* __restrict__ Xb) {
  size_t i = ((size_t)blockIdx.x * 256 + threadIdx.x) * 8;
  const f32x4* src = (const f32x4*)(X + i);
  f32x4 a = src[0], b = src[1];
  bf16x8 v;
  v[0] = (__bf16)a[0]; v[1] = (__bf16)a[1]; v[2] = (__bf16)a[2]; v[3] = (__bf16)a[3];
  v[4] = (__bf16)b[0]; v[5] = (__bf16)b[1]; v[6] = (__bf16)b[2]; v[7] = (__bf16)b[3];
  *(bf16x8*)(Xb + i) = v;
}

// ---------------- pass 1b: int4 group-dequant -> bf16 ----------------------
__global__ __launch_bounds__(256) void deq_w(const int* __restrict__ P,
                                             const float* __restrict__ S,
                                             const float* __restrict__ O,
                                             __bf16* __restrict__ Wb) {
  size_t i = (size_t)blockIdx.x * 256 + threadIdx.x;
  const i32x4* src = (const i32x4*)(P + i * 16);
  int g = (int)(i >> 2);
  float s = S[g], o = O[g];
  __bf16* dst = Wb + i * 32;
#pragma unroll
  for (int j = 0; j < 4; ++j) {
    i32x4 p = src[j];
    bf16x8 v;
#pragma unroll
    for (int b = 0; b < 4; ++b) {
      int pv = p[b];
      v[2 * b]     = (__bf16)fmaf((float)(pv & 15), s, o);
      v[2 * b + 1] = (__bf16)fmaf((float)((pv >> 4) & 15), s, o);
    }
    *(bf16x8*)(dst + j * 8) = v;
  }
}

// stage one 64-row x 64-col chunk (8 KiB). LDS dest linear; global source
// col pre-XOR-swizzled (rule #21).
__device__ __forceinline__ void stage64(const char* g, size_t rs, char* l, int tid) {
  const int r = tid >> 3;
  const int c = ((tid & 7) * 16) ^ ((r & 7) << 4);
  __builtin_amdgcn_global_load_lds(
      (const __attribute__((address_space(1))) uint32_t*)(g + (size_t)r * rs + c),
      (__attribute__((address_space(3))) uint32_t*)(l + (tid >> 6) * 1024),
      16, 0, 0);
}

__device__ __forceinline__ void read_a(bf16x8 (&dst)[4], const char* Ab,
                                       int wm, int ln15, int lq, int mh, int ks) {
#pragma unroll
  for (int m4 = 0; m4 < 4; ++m4) {
    const int r = wm * 128 + (mh * 4 + m4) * 16 + ln15;
    const int sw = (r & 7) << 4;
    dst[m4] = *(const bf16x8*)(Ab + r * 128 + ((ks * 64 + lq * 16) ^ sw));
  }
}

__device__ __forceinline__ void read_b(bf16x8 (&dst)[4], const char* Bb,
                                       int wn, int ln15, int lq, int ks) {
#pragma unroll
  for (int n = 0; n < 4; ++n) {
    const int r = wn * 64 + n * 16 + ln15;
    const int sw = (r & 7) << 4;
    dst[n] = *(const bf16x8*)(Bb + r * 128 + ((ks * 64 + lq * 16) ^ sw));
  }
}

__device__ __forceinline__ void mfma16(f32x4 (&acc)[8][4], const bf16x8 (&af)[4],
                                       const bf16x8 (&bf)[4], int mbase) {
  __builtin_amdgcn_s_setprio(1);
#pragma unroll
  for (int m4 = 0; m4 < 4; ++m4)
#pragma unroll
    for (int n = 0; n < 4; ++n)
      acc[mbase + m4][n] = __builtin_amdgcn_mfma_f32_16x16x32_bf16(
          af[m4], bf[n], acc[mbase + m4][n], 0, 0, 0);
  __builtin_amdgcn_s_setprio(0);
}

// ----- pass 2: 256x256x64 4-phase deep-prefetch bf16 GEMM (Scheme D) -------
__global__ __launch_bounds__(512, 2) void gemm8(const __bf16* __restrict__ A,
                                                const __bf16* __restrict__ B,
                                                const float* __restrict__ Bias,
                                                float* __restrict__ Y) {
  extern __shared__ char lds[];  // [A b0|A b1|B b0|B b1] = 4 x 32 KiB

  constexpr int NT = K_DIM / 64;
  const int tid  = threadIdx.x;
  const int lane = tid & 63;
  const int wid  = tid >> 6;
  const int wm   = wid >> 2;
  const int wn   = wid & 3;
  const int ln15 = lane & 15;
  const int lq   = lane >> 4;

  // T1: bijective XCD swizzle (nwg = 512, 512 % 8 == 0)
  const int id  = blockIdx.y * gridDim.x + blockIdx.x;
  const int swz = (id & 7) * 64 + (id >> 3);
  const int bn0 = (swz & 15) * 256;
  const int bm0 = (swz >> 4) * 256;

  const size_t rs = (size_t)K_DIM * 2;
  const char* Ag = (const char*)A + (size_t)bm0 * rs;
  const char* Bg = (const char*)B + (size_t)bn0 * rs;

  f32x4 acc[8][4];
#pragma unroll
  for (int m = 0; m < 8; ++m)
#pragma unroll
    for (int n = 0; n < 4; ++n)
      acc[m][n] = (f32x4){0.f, 0.f, 0.f, 0.f};

  bf16x8 af0[4], af1[4], bf0[4], bf1[4];

  // ---- prologue: all 8 chunks of tile 0, then B0,B1 of tile 1 ----
  {
    char* Ab = lds;
    char* Bb = lds + 65536;
    stage64(Bg + (size_t)0 * rs,   rs, Bb + 0,     tid);  // B0(0)
    stage64(Bg + (size_t)64 * rs,  rs, Bb + 8192,  tid);  // B1(0)
    stage64(Bg + (size_t)128 * rs, rs, Bb + 16384, tid);  // B2(0)
    stage64(Bg + (size_t)192 * rs, rs, Bb + 24576, tid);  // B3(0)
    stage64(Ag + (size_t)0 * rs,   rs, Ab + 0,     tid);  // A0(0)
    stage64(Ag + (size_t)128 * rs, rs, Ab + 16384, tid);  // A2(0)
    stage64(Ag + (size_t)64 * rs,  rs, Ab + 8192,  tid);  // A1(0)
    stage64(Ag + (size_t)192 * rs, rs, Ab + 24576, tid);  // A3(0)
    char* Bn = lds + 65536 + 32768;
    stage64(Bg + 128,                 rs, Bn + 0,    tid);  // B0(1)
    stage64(Bg + (size_t)64 * rs + 128, rs, Bn + 8192, tid); // B1(1)
  }
  VMCNT(4);   // confirm B0-3,A0,A2 of tile 0; A1,A3(0),B0,B1(1) fly
  SB;
  __builtin_amdgcn_s_barrier();
  read_b(bf0, lds + 65536, wn, ln15, lq, 0);
  read_a(af0, lds,         wm, ln15, lq, 0, 0);

  for (int t = 0; t < NT; ++t) {
    const char* Ab = lds + (t & 1) * 32768;
    const char* Bb = lds + 65536 + (t & 1) * 32768;
    char* An  = lds + ((t + 1) & 1) * 32768;
    char* Bn  = lds + 65536 + ((t + 1) & 1) * 32768;
    char* Bn2 = lds + 65536 + (t & 1) * 32768;      // tile t+2 B-buffer
    const bool s1 = (t + 1 < NT);
    const bool s2 = (t + 2 < NT);
    const char* ga1 = Ag + (size_t)(t + 1) * 128;
    const char* gb1 = Bg + (size_t)(t + 1) * 128;
    const char* gb2 = Bg + (size_t)(t + 2) * 128;

    // ---------- q0: MFMA(mh0,ks0) ----------
    LGKMCNT0; SB;
    mfma16(acc, af0, bf0, 0);
    SB;
    if (s1) {
      stage64(gb1 + (size_t)128 * rs, rs, Bn + 16384, tid);  // B2(t+1)
      stage64(gb1 + (size_t)192 * rs, rs, Bn + 24576, tid);  // B3(t+1)
      stage64(ga1,                    rs, An + 0,     tid);  // A0(t+1)
    }
    if (t == NT - 1) { VMCNT(0); } else { VMCNT(5); }  // confirm A1,A3(t)
    SB;
    __builtin_amdgcn_s_barrier();
    read_a(af1, Ab, wm, ln15, lq, 1, 0);

    // ---------- q1: MFMA(mh1,ks0) ----------
    LGKMCNT0; SB;
    mfma16(acc, af1, bf0, 4);
    SB;
    if (s1) {
      stage64(ga1 + (size_t)128 * rs, rs, An + 16384, tid);  // A2(t+1)
      stage64(ga1 + (size_t)64 * rs,  rs, An + 8192,  tid);  // A1(t+1)
      stage64(ga1 + (size_t)192 * rs, rs, An + 24576, tid);  // A3(t+1)
    }
    read_b(bf1, Bb, wn, ln15, lq, 1);
    read_a(af0, Ab, wm, ln15, lq, 0, 1);
    SB;
    __builtin_amdgcn_s_barrier();

    // ---------- q2: MFMA(mh0,ks1) ----------
    LGKMCNT0; SB;
    mfma16(acc, af0, bf1, 0);
    SB;
    read_a(af1, Ab, wm, ln15, lq, 1, 1);
    SB;
    __builtin_amdgcn_s_barrier();

    // ---------- q3: MFMA(mh1,ks1) ----------
    LGKMCNT0; SB;
    mfma16(acc, af1, bf1, 4);
    SB;
    if (s1) {
      VMCNT(2);               // confirm B0-3,A0,A2 of t+1; A1,A3(t+1) fly
      SB;
      __builtin_amdgcn_s_barrier();
      if (s2) {
        stage64(gb2,                   rs, Bn2 + 0,    tid);  // B0(t+2)
        stage64(gb2 + (size_t)64 * rs, rs, Bn2 + 8192, tid);  // B1(t+2)
      }
      read_b(bf0, Bn, wn, ln15, lq, 0);
      read_a(af0, An, wm, ln15, lq, 0, 0);
    }
  }

  // ---- epilogue: bias + fp32 store. C/D: col=lane&15, row=(lane>>4)*4+reg ----
#pragma unroll
  for (int n = 0; n < 4; ++n) {
    const int col = bn0 + wn * 64 + n * 16 + ln15;
    const float bias = Bias[col];
#pragma unroll
    for (int m = 0; m < 8; ++m) {
      const int row0 = bm0 + wm * 128 + m * 16 + lq * 4;
#pragma unroll
      for (int r = 0; r < 4; ++r)
        Y[(size_t)(row0 + r) * N_DIM + col] = acc[m][n][r] + bias;
    }
  }
}

// ------------------- fallback: round-0 fused kernel ------------------------
__global__ __launch_bounds__(256) void qlin_fused_gemm(
    const float* __restrict__ X, const int* __restrict__ P,
    const float* __restrict__ S, const float* __restrict__ Ofs,
    const float* __restrict__ Bias, float* __restrict__ Y)
{
  constexpr int BM = 128, BN = 128, BK = 64;
  constexpr int NT = K_DIM / BK;
  __shared__ __bf16 As[BM * BK];
  __shared__ __bf16 Bs[BN * BK];

  const int tid  = threadIdx.x;
  const int lane = tid & 63;
  const int wv   = tid >> 6;
  const int wr   = (wv >> 1) * 64;
  const int wc   = (wv & 1) * 64;
  const int bn0 = blockIdx.x * BN;
  const int bm0 = blockIdx.y * BM;
  const int srow  = tid >> 1;
  const int shalf = tid & 1;

  const float* xrow = X + (size_t)(bm0 + srow) * K_DIM + shalf * 32;
  const int*   prow = P + (size_t)(bn0 + srow) * (K_DIM / 2) + shalf * 16;
  const int    gbase = (bn0 + srow) * (K_DIM / 128);

  const int rowb = srow * (BK * 2);
  const int sxor = (srow & 7) << 4;
  const int cbb  = shalf * 64;

  f32x4 areg[8];
  i32x4 breg[4];
  float sc, of;

  f32x4 acc[4][4];
#pragma unroll
  for (int i = 0; i < 4; ++i)
#pragma unroll
    for (int j = 0; j < 4; ++j)
      acc[i][j] = (f32x4){0.f, 0.f, 0.f, 0.f};

#pragma unroll
  for (int i = 0; i < 8; ++i) areg[i] = *(const f32x4*)(xrow + 4 * i);
#pragma unroll
  for (int i = 0; i < 4; ++i) breg[i] = *(const i32x4*)(prow + 4 * i);
  sc = S[gbase];
  of = Ofs[gbase];

  for (int kt = 0; kt < NT; ++kt) {
    __syncthreads();
    {
      char* ab = (char*)As + rowb;
      char* bb = (char*)Bs + rowb;
#pragma unroll
      for (int i = 0; i < 4; ++i) {
        bf16x8 v;
        f32x4 u0 = areg[2 * i], u1 = areg[2 * i + 1];
        v[0] = (__bf16)u0[0]; v[1] = (__bf16)u0[1];
        v[2] = (__bf16)u0[2]; v[3] = (__bf16)u0[3];
        v[4] = (__bf16)u1[0]; v[5] = (__bf16)u1[1];
        v[6] = (__bf16)u1[2]; v[7] = (__bf16)u1[3];
        *(bf16x8*)(ab + ((cbb + 16 * i) ^ sxor)) = v;
      }
#pragma unroll
      for (int i = 0; i < 4; ++i) {
        bf16x8 v;
        i32x4 p = breg[i];
#pragma unroll
        for (int j = 0; j < 4; ++j) {
          int pv = p[j];
          v[2 * j]     = (__bf16)fmaf((float)(pv & 15), sc, of);
          v[2 * j + 1] = (__bf16)fmaf((float)((pv >> 4) & 15), sc, of);
        }
        *(bf16x8*)(bb + ((cbb + 16 * i) ^ sxor)) = v;
      }
    }
    if (kt + 1 < NT) {
      const float* xp = xrow + (kt + 1) * BK;
#pragma unroll
      for (int i = 0; i < 8; ++i) areg[i] = *(const f32x4*)(xp + 4 * i);
      const int* pp = prow + (kt + 1) * (BK / 2);
#pragma unroll
      for (int i = 0; i < 4; ++i) breg[i] = *(const i32x4*)(pp + 4 * i);
      int g = gbase + (kt + 1) / 2;
      sc = S[g]; of = Ofs[g];
    }
    __syncthreads();
#pragma unroll
    for (int ks = 0; ks < 2; ++ks) {
      const int cb = ks * 64 + (lane >> 4) * 16;
      bf16x8 afr[4], bfr[4];
#pragma unroll
      for (int m = 0; m < 4; ++m) {
        int r = wr + m * 16 + (lane & 15);
        afr[m] = *(const bf16x8*)((const char*)As + r * (BK * 2) + (cb ^ ((r & 7) << 4)));
      }
#pragma unroll
      for (int n = 0; n < 4; ++n) {
        int r = wc + n * 16 + (lane & 15);
        bfr[n] = *(const bf16x8*)((const char*)Bs + r * (BK * 2) + (cb ^ ((r & 7) << 4)));
      }
#pragma unroll
      for (int m = 0; m < 4; ++m)
#pragma unroll
        for (int n = 0; n < 4; ++n)
          acc[m][n] = __builtin_amdgcn_mfma_f32_16x16x32_bf16(afr[m], bfr[n], acc[m][n], 0, 0, 0);
    }
  }
#pragma unroll
  for (int n = 0; n < 4; ++n) {
    const int col = bn0 + wc + n * 16 + (lane & 15);
    const float bias = Bias[col];
#pragma unroll
    for (int m = 0; m < 4; ++m) {
      const int row0 = bm0 + wr + m * 16 + (lane >> 4) * 4;
#pragma unroll
      for (int r = 0; r < 4; ++r)
        Y[(size_t)(row0 + r) * N_DIM + col] = acc[m][n][r] + bias;
    }
  }
}

extern "C" void kernel_launch(void* const* d_in, const int* in_sizes, int n_in,
                              void* d_out, int out_size, void* d_ws, size_t ws_size,
                              hipStream_t stream) {
  const float* X    = (const float*)d_in[0];
  const int*   P    = (const int*)d_in[1];
  const float* S    = (const float*)d_in[2];
  const float* Ofs  = (const float*)d_in[3];
  const float* Bias = (const float*)d_in[4];
  float* Y = (float*)d_out;

  const size_t xb_bytes = (size_t)M_DIM * K_DIM * 2;
  const size_t wb_bytes = (size_t)N_DIM * K_DIM * 2;

  if (ws_size >= xb_bytes + wb_bytes) {
    __bf16* Xb = (__bf16*)d_ws;
    __bf16* Wb = (__bf16*)((char*)d_ws + xb_bytes);

    cvt_x<<<dim3((M_DIM * K_DIM) / (256 * 8)), dim3(256), 0, stream>>>(X, Xb);
    deq_w<<<dim3((N_DIM * K_DIM) / (256 * 32)), dim3(256), 0, stream>>>(P, S, Ofs, Wb);

    hipFuncSetAttribute((const void*)gemm8,
                        hipFuncAttributeMaxDynamicSharedMemorySize, 131072);
    dim3 grid(N_DIM / 256, M_DIM / 256);  // (16, 32)
    gemm8<<<grid, dim3(512), 131072, stream>>>(Xb, Wb, Bias, Y);
  } else {
    dim3 grid(N_DIM / 128, M_DIM / 128);
    qlin_fused_gemm<<<grid, dim3(256), 0, stream>>>(X, P, S, Ofs, Bias, Y);
  }
}

// Round 6
// 264.840 us; speedup vs baseline: 2.6910x; 1.0133x over previous
//
#include <hip/hip_runtime.h>
#include <stdint.h>

typedef __attribute__((ext_vector_type(4))) float  f32x4;
typedef __attribute__((ext_vector_type(4))) int    i32x4;
typedef __attribute__((ext_vector_type(8))) __bf16 bf16x8;

constexpr int M_DIM = 8192, N_DIM = 4096, K_DIM = 4096;

#define VMCNT(n) asm volatile("s_waitcnt vmcnt(" #n ")" ::: "memory")
#define SB __builtin_amdgcn_sched_barrier(0)

// ---------------- pass 1: fused prep (X cvt + W dequant) -------------------
constexpr int CVT_BLOCKS = (M_DIM * K_DIM) / (256 * 8);   // 16384
constexpr int DEQ_BLOCKS = (N_DIM * K_DIM) / (256 * 32);  // 2048

__global__ __launch_bounds__(256) void prep(const float* __restrict__ X,
                                            const int* __restrict__ P,
                                            const float* __restrict__ S,
                                            const float* __restrict__ O,
                                            __bf16* __restrict__ Xb,
                                            __bf16* __restrict__ Wb) {
  const int b = blockIdx.x;
  if (b < CVT_BLOCKS) {
    size_t i = ((size_t)b * 256 + threadIdx.x) * 8;
    const f32x4* src = (const f32x4*)(X + i);
    f32x4 a = src[0], c = src[1];
    bf16x8 v;
    v[0] = (__bf16)a[0]; v[1] = (__bf16)a[1]; v[2] = (__bf16)a[2]; v[3] = (__bf16)a[3];
    v[4] = (__bf16)c[0]; v[5] = (__bf16)c[1]; v[6] = (__bf16)c[2]; v[7] = (__bf16)c[3];
    *(bf16x8*)(Xb + i) = v;
  } else {
    size_t i = (size_t)(b - CVT_BLOCKS) * 256 + threadIdx.x;  // 32 weights
    const i32x4* src = (const i32x4*)(P + i * 16);
    int g = (int)(i >> 2);
    float s = S[g], o = O[g];
    __bf16* dst = Wb + i * 32;
#pragma unroll
    for (int j = 0; j < 4; ++j) {
      i32x4 p = src[j];
      bf16x8 v;
#pragma unroll
      for (int bb = 0; bb < 4; ++bb) {
        int pv = p[bb];
        v[2 * bb]     = (__bf16)fmaf((float)(pv & 15), s, o);
        v[2 * bb + 1] = (__bf16)fmaf((float)((pv >> 4) & 15), s, o);
      }
      *(bf16x8*)(dst + j * 8) = v;
    }
  }
}

// stage one 64-row x 64-col chunk (8 KiB). LDS dest linear; global source
// col pre-XOR-swizzled (rule #21).
__device__ __forceinline__ void stage64(const char* g, size_t rs, char* l, int tid) {
  const int r = tid >> 3;
  const int c = ((tid & 7) * 16) ^ ((r & 7) << 4);
  __builtin_amdgcn_global_load_lds(
      (const __attribute__((address_space(1))) uint32_t*)(g + (size_t)r * rs + c),
      (__attribute__((address_space(3))) uint32_t*)(l + (tid >> 6) * 1024),
      16, 0, 0);
}

__device__ __forceinline__ void read_a(bf16x8 (&dst)[4], const char* Ab,
                                       int wm, int ln15, int lq, int mh, int ks) {
#pragma unroll
  for (int m4 = 0; m4 < 4; ++m4) {
    const int r = wm * 128 + (mh * 4 + m4) * 16 + ln15;
    const int sw = (r & 7) << 4;
    dst[m4] = *(const bf16x8*)(Ab + r * 128 + ((ks * 64 + lq * 16) ^ sw));
  }
}

__device__ __forceinline__ void read_b(bf16x8 (&dst)[4], const char* Bb,
                                       int wn, int ln15, int lq, int ks) {
#pragma unroll
  for (int n = 0; n < 4; ++n) {
    const int r = wn * 64 + n * 16 + ln15;
    const int sw = (r & 7) << 4;
    dst[n] = *(const bf16x8*)(Bb + r * 128 + ((ks * 64 + lq * 16) ^ sw));
  }
}

__device__ __forceinline__ void mfma16(f32x4 (&acc)[8][4], const bf16x8 (&af)[4],
                                       const bf16x8 (&bf)[4], int mbase) {
  __builtin_amdgcn_s_setprio(1);
#pragma unroll
  for (int m4 = 0; m4 < 4; ++m4)
#pragma unroll
    for (int n = 0; n < 4; ++n)
      acc[mbase + m4][n] = __builtin_amdgcn_mfma_f32_16x16x32_bf16(
          af[m4], bf[n], acc[mbase + m4][n], 0, 0, 0);
  __builtin_amdgcn_s_setprio(0);
}

// -- pass 2: 256x256x64 4-phase GEMM, reads one-phase-ahead, compiler lgkm --
__global__ __launch_bounds__(512, 2) void gemm8(const __bf16* __restrict__ A,
                                                const __bf16* __restrict__ B,
                                                const float* __restrict__ Bias,
                                                float* __restrict__ Y) {
  extern __shared__ char lds[];  // [A b0|A b1|B b0|B b1] = 4 x 32 KiB

  constexpr int NT = K_DIM / 64;
  const int tid  = threadIdx.x;
  const int lane = tid & 63;
  const int wid  = tid >> 6;
  const int wm   = wid >> 2;
  const int wn   = wid & 3;
  const int ln15 = lane & 15;
  const int lq   = lane >> 4;

  // T1: bijective XCD swizzle (nwg = 512, 512 % 8 == 0)
  const int id  = blockIdx.y * gridDim.x + blockIdx.x;
  const int swz = (id & 7) * 64 + (id >> 3);
  const int bn0 = (swz & 15) * 256;
  const int bm0 = (swz >> 4) * 256;

  const size_t rs = (size_t)K_DIM * 2;
  const char* Ag = (const char*)A + (size_t)bm0 * rs;
  const char* Bg = (const char*)B + (size_t)bn0 * rs;

  f32x4 acc[8][4];
#pragma unroll
  for (int m = 0; m < 8; ++m)
#pragma unroll
    for (int n = 0; n < 4; ++n)
      acc[m][n] = (f32x4){0.f, 0.f, 0.f, 0.f};

  bf16x8 af0[4], af1[4], bf0[4], bf1[4];

  // ---- prologue: all 8 chunks of tile 0 + B0,B1 of tile 1 ----
  {
    char* Ab = lds;
    char* Bb = lds + 65536;
    stage64(Bg + (size_t)0 * rs,   rs, Bb + 0,     tid);  // B0(0)
    stage64(Bg + (size_t)64 * rs,  rs, Bb + 8192,  tid);  // B1(0)
    stage64(Bg + (size_t)128 * rs, rs, Bb + 16384, tid);  // B2(0)
    stage64(Bg + (size_t)192 * rs, rs, Bb + 24576, tid);  // B3(0)
    stage64(Ag + (size_t)0 * rs,   rs, Ab + 0,     tid);  // A0(0)
    stage64(Ag + (size_t)64 * rs,  rs, Ab + 8192,  tid);  // A1(0)
    stage64(Ag + (size_t)128 * rs, rs, Ab + 16384, tid);  // A2(0)
    stage64(Ag + (size_t)192 * rs, rs, Ab + 24576, tid);  // A3(0)
    char* Bn = lds + 65536 + 32768;
    stage64(Bg + 128,                   rs, Bn + 0,    tid);   // B0(1)
    stage64(Bg + (size_t)64 * rs + 128, rs, Bn + 8192, tid);   // B1(1)
  }
  VMCNT(2);   // confirm all of tile 0; B0,B1(1) stay in flight
  __builtin_amdgcn_s_barrier();
  SB;
  read_b(bf0, lds + 65536, wn, ln15, lq, 0);
  read_a(af0, lds,         wm, ln15, lq, 0, 0);

  for (int t = 0; t < NT; ++t) {
    const char* Ab = lds + (t & 1) * 32768;
    const char* Bb = lds + 65536 + (t & 1) * 32768;
    char* An  = lds + ((t + 1) & 1) * 32768;
    char* Bn  = lds + 65536 + ((t + 1) & 1) * 32768;
    char* Bn2 = lds + 65536 + (t & 1) * 32768;      // tile t+2 B-buffer
    const bool s1 = (t + 1 < NT);
    const bool s2 = (t + 2 < NT);
    const char* ga1 = Ag + (size_t)(t + 1) * 128;
    const char* gb1 = Bg + (size_t)(t + 1) * 128;
    const char* gb2 = Bg + (size_t)(t + 2) * 128;

    // ---------- q0: MFMA(mh0,ks0); read af1 for q1; stage 3 ----------
    mfma16(acc, af0, bf0, 0);
    if (s1) {
      stage64(gb1 + (size_t)128 * rs, rs, Bn + 16384, tid);  // B2(t+1)
      stage64(gb1 + (size_t)192 * rs, rs, Bn + 24576, tid);  // B3(t+1)
      stage64(ga1,                    rs, An + 0,     tid);  // A0(t+1)
    }
    read_a(af1, Ab, wm, ln15, lq, 1, 0);   // tile-t data, confirmed last tile
    SB;
    __builtin_amdgcn_s_barrier();
    SB;

    // ---------- q1: MFMA(mh1,ks0); read bf1,af0(ks1); stage 3 ----------
    mfma16(acc, af1, bf0, 4);
    if (s1) {
      stage64(ga1 + (size_t)128 * rs, rs, An + 16384, tid);  // A2(t+1)
      stage64(ga1 + (size_t)64 * rs,  rs, An + 8192,  tid);  // A1(t+1)
      stage64(ga1 + (size_t)192 * rs, rs, An + 24576, tid);  // A3(t+1)
    }
    read_b(bf1, Bb, wn, ln15, lq, 1);
    read_a(af0, Ab, wm, ln15, lq, 0, 1);
    SB;
    __builtin_amdgcn_s_barrier();
    SB;

    // ---------- q2: MFMA(mh0,ks1); read af1(ks1) ----------
    mfma16(acc, af0, bf1, 0);
    read_a(af1, Ab, wm, ln15, lq, 1, 1);
    SB;
    __builtin_amdgcn_s_barrier();
    SB;

    // ---------- q3: MFMA(mh1,ks1); stage B0,B1(t+2); confirm t+1 ----------
    mfma16(acc, af1, bf1, 4);
    if (s1) {
      if (s2) {
        stage64(gb2,                   rs, Bn2 + 0,    tid);  // B0(t+2)
        stage64(gb2 + (size_t)64 * rs, rs, Bn2 + 8192, tid);  // B1(t+2)
        VMCNT(2);      // confirm ALL of t+1; B0,B1(t+2) stay in flight
      } else {
        VMCNT(0);      // second-to-last tile: drain
      }
      __builtin_amdgcn_s_barrier();
      SB;
      read_b(bf0, Bn, wn, ln15, lq, 0);   // fresh t+1 data (only exposed reads)
      read_a(af0, An, wm, ln15, lq, 0, 0);
      SB;
    }
  }

  // ---- epilogue: bias + fp32 store. C/D: col=lane&15, row=(lane>>4)*4+reg ----
#pragma unroll
  for (int n = 0; n < 4; ++n) {
    const int col = bn0 + wn * 64 + n * 16 + ln15;
    const float bias = Bias[col];
#pragma unroll
    for (int m = 0; m < 8; ++m) {
      const int row0 = bm0 + wm * 128 + m * 16 + lq * 4;
#pragma unroll
      for (int r = 0; r < 4; ++r)
        Y[(size_t)(row0 + r) * N_DIM + col] = acc[m][n][r] + bias;
    }
  }
}

// ------------------- fallback: round-0 fused kernel ------------------------
__global__ __launch_bounds__(256) void qlin_fused_gemm(
    const float* __restrict__ X, const int* __restrict__ P,
    const float* __restrict__ S, const float* __restrict__ Ofs,
    const float* __restrict__ Bias, float* __restrict__ Y)
{
  constexpr int BM = 128, BN = 128, BK = 64;
  constexpr int NT = K_DIM / BK;
  __shared__ __bf16 As[BM * BK];
  __shared__ __bf16 Bs[BN * BK];

  const int tid  = threadIdx.x;
  const int lane = tid & 63;
  const int wv   = tid >> 6;
  const int wr   = (wv >> 1) * 64;
  const int wc   = (wv & 1) * 64;
  const int bn0 = blockIdx.x * BN;
  const int bm0 = blockIdx.y * BM;
  const int srow  = tid >> 1;
  const int shalf = tid & 1;

  const float* xrow = X + (size_t)(bm0 + srow) * K_DIM + shalf * 32;
  const int*   prow = P + (size_t)(bn0 + srow) * (K_DIM / 2) + shalf * 16;
  const int    gbase = (bn0 + srow) * (K_DIM / 128);

  const int rowb = srow * (BK * 2);
  const int sxor = (srow & 7) << 4;
  const int cbb  = shalf * 64;

  f32x4 areg[8];
  i32x4 breg[4];
  float sc, of;

  f32x4 acc[4][4];
#pragma unroll
  for (int i = 0; i < 4; ++i)
#pragma unroll
    for (int j = 0; j < 4; ++j)
      acc[i][j] = (f32x4){0.f, 0.f, 0.f, 0.f};

#pragma unroll
  for (int i = 0; i < 8; ++i) areg[i] = *(const f32x4*)(xrow + 4 * i);
#pragma unroll
  for (int i = 0; i < 4; ++i) breg[i] = *(const i32x4*)(prow + 4 * i);
  sc = S[gbase];
  of = Ofs[gbase];

  for (int kt = 0; kt < NT; ++kt) {
    __syncthreads();
    {
      char* ab = (char*)As + rowb;
      char* bb = (char*)Bs + rowb;
#pragma unroll
      for (int i = 0; i < 4; ++i) {
        bf16x8 v;
        f32x4 u0 = areg[2 * i], u1 = areg[2 * i + 1];
        v[0] = (__bf16)u0[0]; v[1] = (__bf16)u0[1];
        v[2] = (__bf16)u0[2]; v[3] = (__bf16)u0[3];
        v[4] = (__bf16)u1[0]; v[5] = (__bf16)u1[1];
        v[6] = (__bf16)u1[2]; v[7] = (__bf16)u1[3];
        *(bf16x8*)(ab + ((cbb + 16 * i) ^ sxor)) = v;
      }
#pragma unroll
      for (int i = 0; i < 4; ++i) {
        bf16x8 v;
        i32x4 p = breg[i];
#pragma unroll
        for (int j = 0; j < 4; ++j) {
          int pv = p[j];
          v[2 * j]     = (__bf16)fmaf((float)(pv & 15), sc, of);
          v[2 * j + 1] = (__bf16)fmaf((float)((pv >> 4) & 15), sc, of);
        }
        *(bf16x8*)(bb + ((cbb + 16 * i) ^ sxor)) = v;
      }
    }
    if (kt + 1 < NT) {
      const float* xp = xrow + (kt + 1) * BK;
#pragma unroll
      for (int i = 0; i < 8; ++i) areg[i] = *(const f32x4*)(xp + 4 * i);
      const int* pp = prow + (kt + 1) * (BK / 2);
#pragma unroll
      for (int i = 0; i < 4; ++i) breg[i] = *(const i32x4*)(pp + 4 * i);
      int g = gbase + (kt + 1) / 2;
      sc = S[g]; of = Ofs[g];
    }
    __syncthreads();
#pragma unroll
    for (int ks = 0; ks < 2; ++ks) {
      const int cb = ks * 64 + (lane >> 4) * 16;
      bf16x8 afr[4], bfr[4];
#pragma unroll
      for (int m = 0; m < 4; ++m) {
        int r = wr + m * 16 + (lane & 15);
        afr[m] = *(const bf16x8*)((const char*)As + r * (BK * 2) + (cb ^ ((r & 7) << 4)));
      }
#pragma unroll
      for (int n = 0; n < 4; ++n) {
        int r = wc + n * 16 + (lane & 15);
        bfr[n] = *(const bf16x8*)((const char*)Bs + r * (BK * 2) + (cb ^ ((r & 7) << 4)));
      }
#pragma unroll
      for (int m = 0; m < 4; ++m)
#pragma unroll
        for (int n = 0; n < 4; ++n)
          acc[m][n] = __builtin_amdgcn_mfma_f32_16x16x32_bf16(afr[m], bfr[n], acc[m][n], 0, 0, 0);
    }
  }
#pragma unroll
  for (int n = 0; n < 4; ++n) {
    const int col = bn0 + wc + n * 16 + (lane & 15);
    const float bias = Bias[col];
#pragma unroll
    for (int m = 0; m < 4; ++m) {
      const int row0 = bm0 + wr + m * 16 + (lane >> 4) * 4;
#pragma unroll
      for (int r = 0; r < 4; ++r)
        Y[(size_t)(row0 + r) * N_DIM + col] = acc[m][n][r] + bias;
    }
  }
}

extern "C" void kernel_launch(void* const* d_in, const int* in_sizes, int n_in,
                              void* d_out, int out_size, void* d_ws, size_t ws_size,
                              hipStream_t stream) {
  const float* X    = (const float*)d_in[0];
  const int*   P    = (const int*)d_in[1];
  const float* S    = (const float*)d_in[2];
  const float* Ofs  = (const float*)d_in[3];
  const float* Bias = (const float*)d_in[4];
  float* Y = (float*)d_out;

  const size_t xb_bytes = (size_t)M_DIM * K_DIM * 2;
  const size_t wb_bytes = (size_t)N_DIM * K_DIM * 2;

  if (ws_size >= xb_bytes + wb_bytes) {
    __bf16* Xb = (__bf16*)d_ws;
    __bf16* Wb = (__bf16*)((char*)d_ws + xb_bytes);

    prep<<<dim3(CVT_BLOCKS + DEQ_BLOCKS), dim3(256), 0, stream>>>(X, P, S, Ofs, Xb, Wb);

    hipFuncSetAttribute((const void*)gemm8,
                        hipFuncAttributeMaxDynamicSharedMemorySize, 131072);
    dim3 grid(N_DIM / 256, M_DIM / 256);  // (16, 32)
    gemm8<<<grid, dim3(512), 131072, stream>>>(Xb, Wb, Bias, Y);
  } else {
    dim3 grid(N_DIM / 128, M_DIM / 128);
    qlin_fused_gemm<<<grid, dim3(256), 0, stream>>>(X, P, S, Ofs, Bias, Y);
  }
}